// Round 1
// baseline (798.083 us; speedup 1.0000x reference)
//
#include <hip/hip_runtime.h>
#include <math.h>

// PointCNN XConv dims (fixed by the problem)
#define NB 32
#define NUM_PT 2048
#define PP 1024
#define KNB 16      // K neighbors
#define CIN 64
#define CHALF 64
#define CMID 32
#define CCAT 96
#define COUT 128
#define QQ 256      // K*K
#define MPB 8       // points per block in k_xconv

#define BN_INV 0.9999950000374996f

static __device__ __forceinline__ float eluf(float x) {
    return x > 0.0f ? x : expm1f(x);
}

// ---------------------------------------------------------------------------
// Kernel 1: fts_l = d0_g * (elu(fts @ d0_W + d0_b) * BN_INV) + d0_be
// 65536 rows x 64 -> 64. Block = 256 threads handles 64 rows.
// W column kept in 64 VGPRs per thread (c = tid&63); rows staged in padded LDS.
// ---------------------------------------------------------------------------
__global__ __launch_bounds__(256) void k_dense0(
    const float* __restrict__ fts, const float* __restrict__ W,
    const float* __restrict__ b, const float* __restrict__ g,
    const float* __restrict__ be, float* __restrict__ out)
{
    __shared__ __align__(16) float rows[64 * 68];   // pad 64 -> 68 (16B-aligned rows)
    const int tid = threadIdx.x;
    const long base = (long)blockIdx.x * (64 * CIN);

    for (int i = tid; i < 64 * 64; i += 256)
        rows[(i >> 6) * 68 + (i & 63)] = fts[base + i];

    const int c = tid & 63;
    const int rg = tid >> 6;
    float wreg[64];
    #pragma unroll
    for (int d = 0; d < 64; ++d) wreg[d] = W[d * 64 + c];
    const float bc = b[c], gc = g[c], bec = be[c];
    __syncthreads();

    for (int i = 0; i < 16; ++i) {
        const int r = rg + (i << 2);
        float acc = bc;
        #pragma unroll
        for (int dq = 0; dq < 16; ++dq) {
            const float4 xv = *(const float4*)&rows[r * 68 + dq * 4];
            acc += xv.x * wreg[dq * 4 + 0] + xv.y * wreg[dq * 4 + 1]
                 + xv.z * wreg[dq * 4 + 2] + xv.w * wreg[dq * 4 + 3];
        }
        out[base + r * 64 + c] = gc * (eluf(acc) * BN_INV) + bec;
    }
}

// ---------------------------------------------------------------------------
// Kernel 2: everything else, fused. One block = 8 points of one batch.
// ---------------------------------------------------------------------------
__global__ __launch_bounds__(256) void k_xconv(
    const float* __restrict__ rep_pts, const float* __restrict__ pts,
    const int* __restrict__ pts_idx, const float* __restrict__ fts_l,
    const float* __restrict__ d1W, const float* __restrict__ d1b,
    const float* __restrict__ d1g, const float* __restrict__ d1be,
    const float* __restrict__ d2W, const float* __restrict__ d2b,
    const float* __restrict__ d2g, const float* __restrict__ d2be,
    const float* __restrict__ xcW, const float* __restrict__ xcb,
    const float* __restrict__ xd1W, const float* __restrict__ xd1b,
    const float* __restrict__ xd2W, const float* __restrict__ xd2b,
    const float* __restrict__ dwW, const float* __restrict__ dwb,
    const float* __restrict__ pwW, const float* __restrict__ pwb,
    const float* __restrict__ endg, const float* __restrict__ endbe,
    float* __restrict__ out)
{
    // fts_cat[m][k][0:32) = h2 (lifted coords), [32:96) = gathered fts_l.
    // [32:64) temporarily holds h1 before the gather overwrites it.
    __shared__ __align__(16) float s_cat[MPB * 16 * 96];   // 48 KB
    __shared__ __align__(16) float s_bufA[MPB * 256];      // 8 KB: X0, then X2
    __shared__ __align__(16) float s_bufB[MPB * 256];      // 8 KB: X1, then dw[8][192]
    __shared__ __align__(16) float s_pl[MPB * 16 * 4];     // pts_local, padded d->4
    __shared__ __align__(16) float s_d2W_[32 * 32];        // 4 KB
    __shared__ float s_d1W_[96], s_d1b_[32], s_d1g_[32], s_d1be_[32];
    __shared__ float s_d2b_[32], s_d2g_[32], s_d2be_[32];
    __shared__ int s_idx[MPB * 16];

    const int tid = threadIdx.x;
    const int n  = blockIdx.x >> 7;            // 128 blocks per batch (1024/8)
    const int pb = (blockIdx.x & 127) * MPB;
    const long prow0 = (long)n * PP + pb;

    // --- const preload (small weights reused many times) ---
    if (tid < 96) s_d1W_[tid] = d1W[tid];
    else if (tid < 128) { int c = tid - 96;  s_d1b_[c] = d1b[c]; s_d1g_[c] = d1g[c]; s_d1be_[c] = d1be[c]; }
    else if (tid < 160) { int c = tid - 128; s_d2b_[c] = d2b[c]; s_d2g_[c] = d2g[c]; s_d2be_[c] = d2be[c]; }
    for (int i = tid; i < 1024; i += 256) s_d2W_[i] = d2W[i];

    // --- A/B: neighbor indices + centered local coords ---
    if (tid < 128) {
        const int m = tid >> 4;
        const int k = tid & 15;
        const int idx = pts_idx[(prow0 + m) * KNB + k];
        s_idx[tid] = idx;
        const float* pp = pts + ((long)n * NUM_PT + idx) * 3;
        const float* rp = rep_pts + (prow0 + m) * 3;
        float* dst = &s_pl[tid * 4];
        dst[0] = pp[0] - rp[0];
        dst[1] = pp[1] - rp[1];
        dst[2] = pp[2] - rp[2];
        dst[3] = 0.0f;
    }
    __syncthreads();

    // --- C: h1 = dense1(pts_local) -> cat[:,32:64) ---
    for (int e = tid; e < 4096; e += 256) {
        const int row = e >> 5;         // m*16+k
        const int c = e & 31;
        const float* pl = &s_pl[row * 4];
        float z = s_d1b_[c] + pl[0] * s_d1W_[c] + pl[1] * s_d1W_[32 + c] + pl[2] * s_d1W_[64 + c];
        s_cat[row * 96 + 32 + c] = s_d1g_[c] * (eluf(z) * BN_INV) + s_d1be_[c];
    }
    __syncthreads();

    // --- D: h2 = dense2(h1) -> cat[:,0:32)  (reads [32:64), writes [0:32): disjoint) ---
    for (int e = tid; e < 4096; e += 256) {
        const int row = e >> 5;
        const int c = e & 31;
        float z = s_d2b_[c];
        #pragma unroll
        for (int jq = 0; jq < 8; ++jq) {
            const float4 hv = *(const float4*)&s_cat[row * 96 + 32 + jq * 4];
            z += hv.x * s_d2W_[(jq * 4 + 0) * 32 + c] + hv.y * s_d2W_[(jq * 4 + 1) * 32 + c]
               + hv.z * s_d2W_[(jq * 4 + 2) * 32 + c] + hv.w * s_d2W_[(jq * 4 + 3) * 32 + c];
        }
        s_cat[row * 96 + c] = s_d2g_[c] * (eluf(z) * BN_INV) + s_d2be_[c];
    }
    __syncthreads();

    // --- E: gather lifted features -> cat[:,32:96) (overwrites dead h1) ---
    #pragma unroll
    for (int i = 0; i < 8; ++i) {
        const int e = tid + i * 256;        // 0..2047 float4 slots
        const int row = e >> 4;             // 0..127
        const int f4 = e & 15;
        const float4 v = *(const float4*)&fts_l[((long)n * NUM_PT + s_idx[row]) * CHALF + f4 * 4];
        *(float4*)&s_cat[row * 96 + 32 + f4 * 4] = v;
    }

    // --- F: X0[q] = elu(sum_{k,d} pl[k][d]*xcW[q][d][k] + xcb[q]) -> bufA ---
    {
        const int q = tid;
        float w0[16], w1[16], w2[16];
        #pragma unroll
        for (int kq = 0; kq < 4; ++kq) {
            const float4 a = *(const float4*)&xcW[q * 48 + 0 * 16 + kq * 4];
            const float4 bb = *(const float4*)&xcW[q * 48 + 1 * 16 + kq * 4];
            const float4 cc = *(const float4*)&xcW[q * 48 + 2 * 16 + kq * 4];
            w0[kq*4+0]=a.x;  w0[kq*4+1]=a.y;  w0[kq*4+2]=a.z;  w0[kq*4+3]=a.w;
            w1[kq*4+0]=bb.x; w1[kq*4+1]=bb.y; w1[kq*4+2]=bb.z; w1[kq*4+3]=bb.w;
            w2[kq*4+0]=cc.x; w2[kq*4+1]=cc.y; w2[kq*4+2]=cc.z; w2[kq*4+3]=cc.w;
        }
        const float bq = xcb[q];
        #pragma unroll
        for (int m = 0; m < MPB; ++m) {
            float acc = bq;
            #pragma unroll
            for (int k = 0; k < 16; ++k) {
                const float4 plv = *(const float4*)&s_pl[(m * 16 + k) * 4];
                acc += plv.x * w0[k] + plv.y * w1[k] + plv.z * w2[k];
            }
            s_bufA[m * 256 + q] = eluf(acc);
        }
    }
    __syncthreads();

    // --- G: X1 = elu(X0 @ xd1W + xd1b) -> bufB.  Thread owns column q for all 8 pts. ---
    {
        const int q = tid;
        const float bq = xd1b[q];
        float acc[MPB];
        #pragma unroll
        for (int m = 0; m < MPB; ++m) acc[m] = bq;
        for (int jq = 0; jq < 64; ++jq) {
            const float w0_ = xd1W[(jq * 4 + 0) * 256 + q];
            const float w1_ = xd1W[(jq * 4 + 1) * 256 + q];
            const float w2_ = xd1W[(jq * 4 + 2) * 256 + q];
            const float w3_ = xd1W[(jq * 4 + 3) * 256 + q];
            #pragma unroll
            for (int m = 0; m < MPB; ++m) {
                const float4 xv = *(const float4*)&s_bufA[m * 256 + jq * 4];
                acc[m] += xv.x * w0_ + xv.y * w1_ + xv.z * w2_ + xv.w * w3_;
            }
        }
        __syncthreads();
        #pragma unroll
        for (int m = 0; m < MPB; ++m) s_bufB[m * 256 + q] = eluf(acc[m]);
    }
    __syncthreads();

    // --- G2: X2 = X1 @ xd2W + xd2b -> bufA (no elu) ---
    {
        const int q = tid;
        const float bq = xd2b[q];
        float acc[MPB];
        #pragma unroll
        for (int m = 0; m < MPB; ++m) acc[m] = bq;
        for (int jq = 0; jq < 64; ++jq) {
            const float w0_ = xd2W[(jq * 4 + 0) * 256 + q];
            const float w1_ = xd2W[(jq * 4 + 1) * 256 + q];
            const float w2_ = xd2W[(jq * 4 + 2) * 256 + q];
            const float w3_ = xd2W[(jq * 4 + 3) * 256 + q];
            #pragma unroll
            for (int m = 0; m < MPB; ++m) {
                const float4 xv = *(const float4*)&s_bufB[m * 256 + jq * 4];
                acc[m] += xv.x * w0_ + xv.y * w1_ + xv.z * w2_ + xv.w * w3_;
            }
        }
        __syncthreads();
        #pragma unroll
        for (int m = 0; m < MPB; ++m) s_bufA[m * 256 + q] = acc[m];
    }
    __syncthreads();

    // --- H: fts_X[i][c] = sum_j X2[i][j]*cat[j][c]; then depthwise -> bufB dw[m][192] ---
    {
        const int m = tid >> 5;
        const int l = tid & 31;
        for (int it = 0; it < 3; ++it) {
            const int c = l + it * 32;
            float acc[16];
            #pragma unroll
            for (int k = 0; k < 16; ++k) acc[k] = 0.0f;
            #pragma unroll
            for (int jt = 0; jt < 4; ++jt) {
                const float c0 = s_cat[(m * 16 + jt * 4 + 0) * 96 + c];
                const float c1 = s_cat[(m * 16 + jt * 4 + 1) * 96 + c];
                const float c2 = s_cat[(m * 16 + jt * 4 + 2) * 96 + c];
                const float c3 = s_cat[(m * 16 + jt * 4 + 3) * 96 + c];
                #pragma unroll
                for (int k = 0; k < 16; ++k) {
                    const float4 xv = *(const float4*)&s_bufA[m * 256 + k * 16 + jt * 4];
                    acc[k] += xv.x * c0 + xv.y * c1 + xv.z * c2 + xv.w * c3;
                }
            }
            #pragma unroll
            for (int dm = 0; dm < 2; ++dm) {
                const int ch = c * 2 + dm;     // channel layout c*DM+dm
                float z = dwb[ch];
                #pragma unroll
                for (int kq = 0; kq < 4; ++kq) {
                    const float4 wv = *(const float4*)&dwW[ch * 16 + kq * 4];
                    z += acc[kq * 4 + 0] * wv.x + acc[kq * 4 + 1] * wv.y
                       + acc[kq * 4 + 2] * wv.z + acc[kq * 4 + 3] * wv.w;
                }
                s_bufB[m * 192 + ch] = z;
            }
        }
    }
    __syncthreads();

    // --- I: out = end_g*(elu(dw @ pwW + pwb)*BN_INV) + end_be ---
    {
        const int o = tid & 127;
        const int mg = tid >> 7;   // 0 or 1; thread covers m = mg, mg+2, mg+4, mg+6
        const float bo = pwb[o], go = endg[o], beo = endbe[o];
        float acc[4];
        #pragma unroll
        for (int i = 0; i < 4; ++i) acc[i] = bo;
        for (int cq = 0; cq < 48; ++cq) {
            const float w0_ = pwW[(cq * 4 + 0) * 128 + o];
            const float w1_ = pwW[(cq * 4 + 1) * 128 + o];
            const float w2_ = pwW[(cq * 4 + 2) * 128 + o];
            const float w3_ = pwW[(cq * 4 + 3) * 128 + o];
            #pragma unroll
            for (int i = 0; i < 4; ++i) {
                const int m = mg + i * 2;
                const float4 dv = *(const float4*)&s_bufB[m * 192 + cq * 4];
                acc[i] += dv.x * w0_ + dv.y * w1_ + dv.z * w2_ + dv.w * w3_;
            }
        }
        #pragma unroll
        for (int i = 0; i < 4; ++i) {
            const int m = mg + i * 2;
            out[(prow0 + m) * COUT + o] = go * (eluf(acc[i]) * BN_INV) + beo;
        }
    }
}

extern "C" void kernel_launch(void* const* d_in, const int* in_sizes, int n_in,
                              void* d_out, int out_size, void* d_ws, size_t ws_size,
                              hipStream_t stream) {
    const float* rep_pts = (const float*)d_in[0];
    const float* pts     = (const float*)d_in[1];
    const float* fts     = (const float*)d_in[2];
    const int*   pts_idx = (const int*)d_in[3];
    const float* d0W = (const float*)d_in[4];
    const float* d0b = (const float*)d_in[5];
    const float* d0g = (const float*)d_in[6];
    const float* d0be = (const float*)d_in[7];
    const float* d1W = (const float*)d_in[8];
    const float* d1b = (const float*)d_in[9];
    const float* d1g = (const float*)d_in[10];
    const float* d1be = (const float*)d_in[11];
    const float* d2W = (const float*)d_in[12];
    const float* d2b = (const float*)d_in[13];
    const float* d2g = (const float*)d_in[14];
    const float* d2be = (const float*)d_in[15];
    const float* xcW = (const float*)d_in[16];
    const float* xcb = (const float*)d_in[17];
    const float* xd1W = (const float*)d_in[18];
    const float* xd1b = (const float*)d_in[19];
    const float* xd2W = (const float*)d_in[20];
    const float* xd2b = (const float*)d_in[21];
    const float* dwW = (const float*)d_in[22];
    const float* dwb = (const float*)d_in[23];
    const float* pwW = (const float*)d_in[24];
    const float* pwb = (const float*)d_in[25];
    const float* endg = (const float*)d_in[26];
    const float* endbe = (const float*)d_in[27];
    float* out = (float*)d_out;

    float* fts_l = (float*)d_ws;   // 32*2048*64 floats = 16.8 MB scratch

    // Kernel 1: lift raw features
    k_dense0<<<(NB * NUM_PT) / 64, 256, 0, stream>>>(fts, d0W, d0b, d0g, d0be, fts_l);

    // Kernel 2: fused XConv (gather, lifting MLP, X-transform, fts_X, dw, pw, BN)
    k_xconv<<<NB * (PP / MPB), 256, 0, stream>>>(
        rep_pts, pts, pts_idx, fts_l,
        d1W, d1b, d1g, d1be, d2W, d2b, d2g, d2be,
        xcW, xcb, xd1W, xd1b, xd2W, xd2b,
        dwW, dwb, pwW, pwb, endg, endbe, out);
}

// Round 2
// 209.499 us; speedup vs baseline: 3.8095x; 3.8095x over previous
//
#include <hip/hip_runtime.h>
#include <math.h>

// PointCNN XConv dims (fixed)
#define NBATCH 32
#define NUMPT 2048
#define PP 1024
#define MPB 16                 // points per block in k_xconv
#define BN_INV 0.9999950000374996f

typedef __attribute__((ext_vector_type(8))) short short8;   // 8 bf16 (4 VGPRs)
typedef __attribute__((ext_vector_type(4))) float f32x4;    // MFMA C/D

#define MFMA(a,b,c) __builtin_amdgcn_mfma_f32_16x16x32_bf16(a,b,c,0,0,0)

// ws layout (elements of short): fts_l bf16 [32][2048][64], then frag weights
#define FTSL_ELEMS 4194304
#define OFF_D0F  0           // [2kt][4nb][64][8]   K=64  N=64
#define OFF_XCF  4096        // [2kt][16nb][64][8]  K=64(48 valid) N=256
#define OFF_X1F  20480       // [8kt][16nb][64][8]  K=256 N=256
#define OFF_X2F  86016       // [8kt][16nb][64][8]
#define OFF_D2F  151552      // [1kt][2nb][64][8]   K=32  N=32
#define OFF_PWF  152576      // [6kt][8nb][64][8]   K=192 N=128
#define TOT_FRAG 177152

static __device__ __forceinline__ float eluf(float x) {
    return x > 0.0f ? x : (__expf(x) - 1.0f);
}
static __device__ __forceinline__ short f2bf(float x) {   // RNE fp32->bf16
    union { float f; unsigned u; } v; v.f = x;
    unsigned r = v.u + 0x7FFFu + ((v.u >> 16) & 1u);
    return (short)(r >> 16);
}

// ---------------------------------------------------------------------------
// Prep: convert weight matrices to B-fragment-ordered bf16.
// B[k][n] frag elem: lane(n=lane&15, quad=lane>>4), j: k = kt*32+quad*8+j.
// Linear: ((kt*NT + nb)*64 + lane)*8 + j
// ---------------------------------------------------------------------------
__global__ __launch_bounds__(256) void k_prep(
    const float* __restrict__ d0W, const float* __restrict__ xcW,
    const float* __restrict__ xd1W, const float* __restrict__ xd2W,
    const float* __restrict__ d2W, const float* __restrict__ pwW,
    short* __restrict__ wf)
{
    int gid = blockIdx.x * 256 + threadIdx.x;
    if (gid >= TOT_FRAG) return;
    float val;
    if (gid < OFF_XCF) {
        int e = gid, j = e & 7, lane = (e >> 3) & 63, t = e >> 9;
        int nb = t % 4, kt = t / 4;
        int nn = nb * 16 + (lane & 15), k = kt * 32 + (lane >> 4) * 8 + j;
        val = d0W[k * 64 + nn];
    } else if (gid < OFF_X1F) {
        int e = gid - OFF_XCF, j = e & 7, lane = (e >> 3) & 63, t = e >> 9;
        int nb = t % 16, kt = t / 16;
        int q = nb * 16 + (lane & 15), kk = kt * 32 + (lane >> 4) * 8 + j;
        // kk = d*16 + kn (48 valid), src xcW[(q*3 + d)*16 + kn]
        val = (kk < 48) ? xcW[(q * 3 + (kk >> 4)) * 16 + (kk & 15)] : 0.0f;
    } else if (gid < OFF_X2F) {
        int e = gid - OFF_X1F, j = e & 7, lane = (e >> 3) & 63, t = e >> 9;
        int nb = t % 16, kt = t / 16;
        int nn = nb * 16 + (lane & 15), k = kt * 32 + (lane >> 4) * 8 + j;
        val = xd1W[k * 256 + nn];
    } else if (gid < OFF_D2F) {
        int e = gid - OFF_X2F, j = e & 7, lane = (e >> 3) & 63, t = e >> 9;
        int nb = t % 16, kt = t / 16;
        int nn = nb * 16 + (lane & 15), k = kt * 32 + (lane >> 4) * 8 + j;
        val = xd2W[k * 256 + nn];
    } else if (gid < OFF_PWF) {
        int e = gid - OFF_D2F, j = e & 7, lane = (e >> 3) & 63, t = e >> 9;
        int nb = t % 2;
        int nn = nb * 16 + (lane & 15), k = (lane >> 4) * 8 + j;
        val = d2W[k * 32 + nn];
    } else {
        int e = gid - OFF_PWF, j = e & 7, lane = (e >> 3) & 63, t = e >> 9;
        int nb = t % 8, kt = t / 8;
        int nn = nb * 16 + (lane & 15), k = kt * 32 + (lane >> 4) * 8 + j;
        val = pwW[k * 128 + nn];
    }
    wf[gid] = f2bf(val);
}

// ---------------------------------------------------------------------------
// dense0 via MFMA: 65536x64 @ 64x64, 64 rows/block, bf16 output to ws.
// ---------------------------------------------------------------------------
__global__ __launch_bounds__(256) void k_dense0m(
    const float* __restrict__ fts, const short* __restrict__ wf,
    const float* __restrict__ b, const float* __restrict__ g,
    const float* __restrict__ be, short* __restrict__ fl)
{
    __shared__ __align__(16) short sA[4096];   // A frags: [2kt][4mt][64][8]
    const int tid = threadIdx.x;
    const long base = (long)blockIdx.x * 64 * 64;
    {
        const int r = tid >> 2, k0 = (tid & 3) * 16;
        #pragma unroll
        for (int i = 0; i < 4; ++i) {
            float4 v = *(const float4*)&fts[base + r * 64 + k0 + i * 4];
            float vv[4] = {v.x, v.y, v.z, v.w};
            #pragma unroll
            for (int u = 0; u < 4; ++u) {
                int k = k0 + i * 4 + u;
                sA[(((k >> 5) * 4 + (r >> 4)) * 64 + ((r & 15) + 16 * ((k >> 3) & 3))) * 8 + (k & 7)] = f2bf(vv[u]);
            }
        }
    }
    __syncthreads();
    const int wave = tid >> 6, lane = tid & 63;
    const int col = lane & 15, quad = lane >> 4;
    const int c = wave * 16 + col;
    const float bb = b[c], gg = g[c], bee = be[c];
    const f32x4 fz = {0.f, 0.f, 0.f, 0.f};
    f32x4 acc[4] = {fz, fz, fz, fz};
    const short8* B = (const short8*)(wf + OFF_D0F);
    #pragma unroll
    for (int kt = 0; kt < 2; ++kt) {
        short8 bfr = B[(kt * 4 + wave) * 64 + lane];
        #pragma unroll
        for (int mt = 0; mt < 4; ++mt) {
            short8 afr = *(const short8*)&sA[((kt * 4 + mt) * 64 + lane) * 8];
            acc[mt] = MFMA(afr, bfr, acc[mt]);
        }
    }
    #pragma unroll
    for (int mt = 0; mt < 4; ++mt) {
        #pragma unroll
        for (int r = 0; r < 4; ++r) {
            long row = (long)blockIdx.x * 64 + mt * 16 + quad * 4 + r;
            fl[row * 64 + c] = f2bf(gg * (eluf(acc[mt][r] + bb) * BN_INV) + bee);
        }
    }
}

// ---------------------------------------------------------------------------
// Fused XConv: 16 points/block, 256 threads (4 waves), MFMA everywhere.
// ---------------------------------------------------------------------------
__global__ __launch_bounds__(256) void k_xconv(
    const float* __restrict__ rep_pts, const float* __restrict__ pts,
    const int* __restrict__ pts_idx, const short* __restrict__ fl,
    const short* __restrict__ wf,
    const float* __restrict__ d1W, const float* __restrict__ d1b,
    const float* __restrict__ d1g, const float* __restrict__ d1be,
    const float* __restrict__ d2b, const float* __restrict__ d2g,
    const float* __restrict__ d2be,
    const float* __restrict__ xcb, const float* __restrict__ xd1b,
    const float* __restrict__ xd2b,
    const float* __restrict__ dwW, const float* __restrict__ dwb,
    const float* __restrict__ pwb,
    const float* __restrict__ endg, const float* __restrict__ endbe,
    float* __restrict__ out)
{
    // catF: per-point B-frag layout for H: [p][((nb*2+quad)*16+n)*8+j], K=16
    __shared__ __align__(16) short s_catF[24576];   // 48 KB
    __shared__ __align__(16) short s_big[8192];     // h1F(16K) -> X1(8K)+X2(8K)
    __shared__ __align__(16) short s_X0b[4096];     // X0 frags -> dwF frags
    __shared__ __align__(16) short s_plF[1024];     // pl A-frags, K=64 (48 valid)
    __shared__ float s_pl[768];                     // pl fp32 [256 rows][3]
    __shared__ float s_d1w[192];                    // d1W(96) b(32) g(32) be(32)

    const int tid = threadIdx.x;
    const int wave = tid >> 6, lane = tid & 63;
    const int col = lane & 15, quad = lane >> 4;
    const int n = blockIdx.x >> 6;                  // 64 blocks per batch
    const int pb = (blockIdx.x & 63) * MPB;
    const long prow0 = (long)n * PP + pb;
    short* s_h1F = s_big;
    short* s_X1 = s_big;
    short* s_X2 = s_big + 4096;
    short* s_dwF = s_X0b;
    const f32x4 fz = {0.f, 0.f, 0.f, 0.f};
    const short8 zz = {0, 0, 0, 0, 0, 0, 0, 0};

    // ---- S0: pad-zero plF tail, small weights, idx + local coords ----
    for (int i = 768 + tid; i < 1024; i += 256) s_plF[i] = 0;  // kk>=48 pad
    if (tid < 96) s_d1w[tid] = d1W[tid];
    else if (tid < 128) { int cc = tid - 96; s_d1w[96 + cc] = d1b[cc]; s_d1w[128 + cc] = d1g[cc]; s_d1w[160 + cc] = d1be[cc]; }
    const int p0 = tid >> 4, k0 = tid & 15;
    const int idxv = pts_idx[(prow0 + p0) * 16 + k0];
    {
        const float* pp = pts + ((long)n * NUMPT + idxv) * 3;
        const float* rp = rep_pts + (prow0 + p0) * 3;
        #pragma unroll
        for (int d = 0; d < 3; ++d) {
            float v = pp[d] - rp[d];
            s_pl[tid * 3 + d] = v;
            int kk = d * 16 + k0;                        // contraction index for F
            s_plF[((kk >> 5) * 64 + ((kk >> 3) & 3) * 16 + p0) * 8 + (kk & 7)] = f2bf(v);
        }
    }
    __syncthreads();

    // ---- E loads (issue early), S1: d1 -> h1F, E writes ----
    short8 gv[8];
    {
        const short8* gp = (const short8*)(fl + ((long)n * NUMPT + idxv) * 64);
        #pragma unroll
        for (int i = 0; i < 8; ++i) gv[i] = gp[i];
    }
    for (int e = tid; e < 8192; e += 256) {             // 256 rows x 32 cols
        int row = e >> 5, c1 = e & 31;
        float x0 = s_pl[row * 3], x1 = s_pl[row * 3 + 1], x2 = s_pl[row * 3 + 2];
        float z = s_d1w[96 + c1] + x0 * s_d1w[c1] + x1 * s_d1w[32 + c1] + x2 * s_d1w[64 + c1];
        float v = s_d1w[128 + c1] * (eluf(z) * BN_INV) + s_d1w[160 + c1];
        // h1 A-frag: m_global = row (p*16+k), mt = p, K=32 single kt
        s_h1F[((row >> 4) * 64 + ((c1 >> 3) & 3) * 16 + (row & 15)) * 8 + (c1 & 7)] = f2bf(v);
    }
    {
        const int kq = k0 >> 3, kj = k0 & 7;
        #pragma unroll
        for (int i = 0; i < 8; ++i) {
            #pragma unroll
            for (int u = 0; u < 8; ++u) {
                int cc = 32 + i * 8 + u;
                s_catF[p0 * 1536 + (((cc >> 4) * 2 + kq) * 16 + (cc & 15)) * 8 + kj] = gv[i][u];
            }
        }
    }
    __syncthreads();

    // ---- D: h2 = dense2(h1) via MFMA (M=256,K=32,N=32) -> catF[:, c<32] ----
    {
        const short8* B = (const short8*)(wf + OFF_D2F);
        short8 b0 = B[lane], b1 = B[64 + lane];
        short8 a[4];
        #pragma unroll
        for (int mt0 = 0; mt0 < 4; ++mt0)
            a[mt0] = *(const short8*)&s_h1F[((wave * 4 + mt0) * 64 + lane) * 8];
        #pragma unroll
        for (int nb = 0; nb < 2; ++nb) {
            int c2 = nb * 16 + col;
            float bb = d2b[c2], gg = d2g[c2], bee = d2be[c2];
            #pragma unroll
            for (int mt0 = 0; mt0 < 4; ++mt0) {
                int mt = wave * 4 + mt0;                 // mt == point p
                f32x4 acc = MFMA(a[mt0], nb ? b1 : b0, fz);
                #pragma unroll
                for (int r = 0; r < 4; ++r) {
                    int k = quad * 4 + r;                // neighbor slot
                    float v = gg * (eluf(acc[r] + bb) * BN_INV) + bee;
                    s_catF[mt * 1536 + ((nb * 2 + (k >> 3)) * 16 + col) * 8 + (k & 7)] = f2bf(v);
                }
            }
        }
    }

    // ---- F: X0 = elu(pl-lift GEMM) (M=16,K=64(48),N=256) -> X0 A-frags ----
    {
        short8 a0 = *(const short8*)&s_plF[lane * 8];
        short8 a1 = *(const short8*)&s_plF[(64 + lane) * 8];
        const short8* B = (const short8*)(wf + OFF_XCF);
        #pragma unroll
        for (int t = 0; t < 4; ++t) {
            int nb = wave * 4 + t;
            f32x4 acc = MFMA(a0, B[nb * 64 + lane], fz);
            acc = MFMA(a1, B[(16 + nb) * 64 + lane], acc);
            int q = nb * 16 + col;
            float bq = xcb[q];
            #pragma unroll
            for (int r = 0; r < 4; ++r) {
                int p = quad * 4 + r;
                float v = eluf(acc[r] + bq);
                s_X0b[((q >> 5) * 64 + ((q >> 3) & 3) * 16 + p) * 8 + (q & 7)] = f2bf(v);
            }
        }
    }
    __syncthreads();

    // ---- G: X1 = elu(X0 @ xd1W + b) (M=16,K=256,N=256) ----
    {
        short8 a[8];
        #pragma unroll
        for (int kt = 0; kt < 8; ++kt)
            a[kt] = *(const short8*)&s_X0b[(kt * 64 + lane) * 8];
        const short8* B = (const short8*)(wf + OFF_X1F);
        #pragma unroll
        for (int t = 0; t < 4; ++t) {
            int nb = wave * 4 + t;
            f32x4 acc = fz;
            #pragma unroll
            for (int kt = 0; kt < 8; ++kt)
                acc = MFMA(a[kt], B[(kt * 16 + nb) * 64 + lane], acc);
            int q = nb * 16 + col;
            float bq = xd1b[q];
            #pragma unroll
            for (int r = 0; r < 4; ++r) {
                int p = quad * 4 + r;
                float v = eluf(acc[r] + bq);
                s_X1[((q >> 5) * 64 + ((q >> 3) & 3) * 16 + p) * 8 + (q & 7)] = f2bf(v);
            }
        }
    }
    __syncthreads();

    // ---- G2: X2 = X1 @ xd2W + b (no elu) -> per-point H A-layout ----
    {
        short8 a[8];
        #pragma unroll
        for (int kt = 0; kt < 8; ++kt)
            a[kt] = *(const short8*)&s_X1[(kt * 64 + lane) * 8];
        const short8* B = (const short8*)(wf + OFF_X2F);
        #pragma unroll
        for (int t = 0; t < 4; ++t) {
            int nb = wave * 4 + t;                       // == i (row of 16x16 X)
            f32x4 acc = fz;
            #pragma unroll
            for (int kt = 0; kt < 8; ++kt)
                acc = MFMA(a[kt], B[(kt * 16 + nb) * 64 + lane], acc);
            float bq = xd2b[nb * 16 + col];              // j = col
            #pragma unroll
            for (int r = 0; r < 4; ++r) {
                int p = quad * 4 + r;
                float v = acc[r] + bq;
                s_X2[p * 256 + ((col >> 3) * 16 + nb) * 8 + (col & 7)] = f2bf(v);
            }
        }
    }
    __syncthreads();

    // ---- H: per-point fts_X = X2(16x16) @ cat(16x96), fused depthwise ----
    {
        float4 wd0[6], wd1[6]; float2 bdw[6];
        #pragma unroll
        for (int nb = 0; nb < 6; ++nb) {
            int c = nb * 16 + col;
            wd0[nb] = *(const float4*)&dwW[(c * 2 + 0) * 16 + quad * 4];
            wd1[nb] = *(const float4*)&dwW[(c * 2 + 1) * 16 + quad * 4];
            bdw[nb] = *(const float2*)&dwb[c * 2];
        }
        #pragma unroll
        for (int pi = 0; pi < 4; ++pi) {
            int p = wave * 4 + pi;
            short8 afr = zz;
            if (lane < 32) afr = *(const short8*)&s_X2[p * 256 + lane * 8];
            #pragma unroll
            for (int nb = 0; nb < 6; ++nb) {
                short8 bfr = zz;
                if (lane < 32) bfr = *(const short8*)&s_catF[p * 1536 + (nb * 32 + lane) * 8];
                f32x4 acc = MFMA(afr, bfr, fz);          // C row = i, col = c
                float q0 = acc[0] * wd0[nb].x + acc[1] * wd0[nb].y + acc[2] * wd0[nb].z + acc[3] * wd0[nb].w;
                float q1 = acc[0] * wd1[nb].x + acc[1] * wd1[nb].y + acc[2] * wd1[nb].z + acc[3] * wd1[nb].w;
                q0 += __shfl_xor(q0, 16); q0 += __shfl_xor(q0, 32);
                q1 += __shfl_xor(q1, 16); q1 += __shfl_xor(q1, 32);
                if (quad == 0) {
                    int c2 = col * 2;                    // kk = nb*32 + c2 + dm
                    int ad = (nb * 64 + (c2 >> 3) * 16 + p) * 8 + (c2 & 7);
                    s_dwF[ad]     = f2bf(q0 + bdw[nb].x);
                    s_dwF[ad + 1] = f2bf(q1 + bdw[nb].y);
                }
            }
        }
    }
    __syncthreads();

    // ---- PW: out = BN(elu(dw @ pwW + b)) (M=16,K=192,N=128) ----
    {
        short8 a[6];
        #pragma unroll
        for (int kt = 0; kt < 6; ++kt)
            a[kt] = *(const short8*)&s_dwF[(kt * 64 + lane) * 8];
        const short8* B = (const short8*)(wf + OFF_PWF);
        #pragma unroll
        for (int t = 0; t < 2; ++t) {
            int nb = wave * 2 + t;
            f32x4 acc = fz;
            #pragma unroll
            for (int kt = 0; kt < 6; ++kt)
                acc = MFMA(a[kt], B[(kt * 8 + nb) * 64 + lane], acc);
            int o = nb * 16 + col;
            float bo = pwb[o], go = endg[o], beo = endbe[o];
            #pragma unroll
            for (int r = 0; r < 4; ++r) {
                int p = quad * 4 + r;
                out[(prow0 + p) * 128 + o] = go * (eluf(acc[r] + bo) * BN_INV) + beo;
            }
        }
    }
}

extern "C" void kernel_launch(void* const* d_in, const int* in_sizes, int n_in,
                              void* d_out, int out_size, void* d_ws, size_t ws_size,
                              hipStream_t stream) {
    const float* rep_pts = (const float*)d_in[0];
    const float* pts     = (const float*)d_in[1];
    const float* fts     = (const float*)d_in[2];
    const int*   pts_idx = (const int*)d_in[3];
    const float* d0W = (const float*)d_in[4];
    const float* d0b = (const float*)d_in[5];
    const float* d0g = (const float*)d_in[6];
    const float* d0be = (const float*)d_in[7];
    const float* d1W = (const float*)d_in[8];
    const float* d1b = (const float*)d_in[9];
    const float* d1g = (const float*)d_in[10];
    const float* d1be = (const float*)d_in[11];
    const float* d2W = (const float*)d_in[12];
    const float* d2b = (const float*)d_in[13];
    const float* d2g = (const float*)d_in[14];
    const float* d2be = (const float*)d_in[15];
    const float* xcW = (const float*)d_in[16];
    const float* xcb = (const float*)d_in[17];
    const float* xd1W = (const float*)d_in[18];
    const float* xd1b = (const float*)d_in[19];
    const float* xd2W = (const float*)d_in[20];
    const float* xd2b = (const float*)d_in[21];
    const float* dwW = (const float*)d_in[22];
    const float* dwb = (const float*)d_in[23];
    const float* pwW = (const float*)d_in[24];
    const float* pwb = (const float*)d_in[25];
    const float* endg = (const float*)d_in[26];
    const float* endbe = (const float*)d_in[27];
    float* out = (float*)d_out;

    short* wsS = (short*)d_ws;
    short* fl = wsS;                    // fts_l bf16: 8.39 MB
    short* wf = wsS + FTSL_ELEMS;       // frag weights: 354 KB

    k_prep<<<TOT_FRAG / 256, 256, 0, stream>>>(d0W, xcW, xd1W, xd2W, d2W, pwW, wf);
    k_dense0m<<<(NBATCH * NUMPT) / 64, 256, 0, stream>>>(fts, wf, d0b, d0g, d0be, fl);
    k_xconv<<<NBATCH * (PP / MPB), 256, 0, stream>>>(
        rep_pts, pts, pts_idx, fl, wf,
        d1W, d1b, d1g, d1be, d2b, d2g, d2be,
        xcb, xd1b, xd2b, dwW, dwb, pwb, endg, endbe, out);
}

// Round 6
// 197.919 us; speedup vs baseline: 4.0324x; 1.0585x over previous
//
#include <hip/hip_runtime.h>
#include <math.h>

// PointCNN XConv dims (fixed)
#define NBATCH 32
#define NUMPT 2048
#define PP 1024
#define MPB 16                 // points per block in k_xconv
#define BN_INV 0.9999950000374996f

typedef __attribute__((ext_vector_type(8))) short short8;   // 8 bf16 (4 VGPRs)
typedef __attribute__((ext_vector_type(4))) short short4v;  // 4 bf16 (b64)
typedef __attribute__((ext_vector_type(2))) short short2v;  // 2 bf16 (b32)
typedef __attribute__((ext_vector_type(4))) float f32x4;    // MFMA C/D

#define MFMA(a,b,c) __builtin_amdgcn_mfma_f32_16x16x32_bf16(a,b,c,0,0,0)

// ws layout (elements of short): fts_l bf16 [32][2048][64], then frag weights
#define FTSL_ELEMS 4194304
#define OFF_D0F  0           // [2kt][4t][64][8]  frags of d0W (A of W^T == B of W)
#define OFF_XCF  4096        // [2kt][16nb][64][8]  K=64(48 valid) N=256
#define OFF_X1F  20480       // [8kt][16nb][64][8]  K=256 N=256
#define OFF_X2F  86016       // [8kt][16nb][64][8]
#define OFF_D2F  151552      // [1kt][2nb][64][8]   K=32  N=32
#define OFF_PWF  152576      // [6kt][8nb][64][8]   K=192 N=128
#define TOT_FRAG 177152

// catF: c-major per point: [p][c 96][k 16], p-stride 1552 shorts (+8 banks)
#define CATP 1552

static __device__ __forceinline__ float eluf(float x) {
    return x > 0.0f ? x : (__expf(x) - 1.0f);
}
static __device__ __forceinline__ short f2bf(float x) {   // RNE fp32->bf16
    union { float f; unsigned u; } v; v.f = x;
    unsigned r = v.u + 0x7FFFu + ((v.u >> 16) & 1u);
    return (short)(r >> 16);
}

// ---------------------------------------------------------------------------
// Prep: weight matrices -> fragment-ordered bf16.
// frag elem: lane(n=lane&15, quad=lane>>4), j: k = kt*32+quad*8+j.
// ---------------------------------------------------------------------------
__global__ __launch_bounds__(256) void k_prep(
    const float* __restrict__ d0W, const float* __restrict__ xcW,
    const float* __restrict__ xd1W, const float* __restrict__ xd2W,
    const float* __restrict__ d2W, const float* __restrict__ pwW,
    short* __restrict__ wf)
{
    int gid = blockIdx.x * 256 + threadIdx.x;
    if (gid >= TOT_FRAG) return;
    float val;
    if (gid < OFF_XCF) {
        int e = gid, j = e & 7, lane = (e >> 3) & 63, t = e >> 9;
        int nb = t % 4, kt = t / 4;
        int nn = nb * 16 + (lane & 15), k = kt * 32 + (lane >> 4) * 8 + j;
        val = d0W[k * 64 + nn];
    } else if (gid < OFF_X1F) {
        int e = gid - OFF_XCF, j = e & 7, lane = (e >> 3) & 63, t = e >> 9;
        int nb = t % 16, kt = t / 16;
        int q = nb * 16 + (lane & 15), kk = kt * 32 + (lane >> 4) * 8 + j;
        val = (kk < 48) ? xcW[(q * 3 + (kk >> 4)) * 16 + (kk & 15)] : 0.0f;
    } else if (gid < OFF_X2F) {
        int e = gid - OFF_X1F, j = e & 7, lane = (e >> 3) & 63, t = e >> 9;
        int nb = t % 16, kt = t / 16;
        int nn = nb * 16 + (lane & 15), k = kt * 32 + (lane >> 4) * 8 + j;
        val = xd1W[k * 256 + nn];
    } else if (gid < OFF_D2F) {
        int e = gid - OFF_X2F, j = e & 7, lane = (e >> 3) & 63, t = e >> 9;
        int nb = t % 16, kt = t / 16;
        int nn = nb * 16 + (lane & 15), k = kt * 32 + (lane >> 4) * 8 + j;
        val = xd2W[k * 256 + nn];
    } else if (gid < OFF_PWF) {
        int e = gid - OFF_D2F, j = e & 7, lane = (e >> 3) & 63, t = e >> 9;
        int nb = t % 2;
        int nn = nb * 16 + (lane & 15), k = (lane >> 4) * 8 + j;
        val = d2W[k * 32 + nn];
    } else {
        int e = gid - OFF_PWF, j = e & 7, lane = (e >> 3) & 63, t = e >> 9;
        int nb = t % 8, kt = t / 8;
        int nn = nb * 16 + (lane & 15), k = kt * 32 + (lane >> 4) * 8 + j;
        val = pwW[k * 128 + nn];
    }
    wf[gid] = f2bf(val);
}

// ---------------------------------------------------------------------------
// dense0 (transposed): D = W0^T (A) @ X^T (B) so C/D rows = channels.
// 128 rows/block; staging via b128 only; output packed b64 stores.
// ---------------------------------------------------------------------------
__global__ __launch_bounds__(256) void k_dense0m(
    const float* __restrict__ fts, const short* __restrict__ wf,
    const float* __restrict__ b, const float* __restrict__ g,
    const float* __restrict__ be, short* __restrict__ fl)
{
    // B-frags of X^T: [kt2][nt8][65 slots][8] (pad 1 slot/nt -> 520 shorts)
    __shared__ __align__(16) short sB[2 * 4160];
    const int tid = threadIdx.x;
    const long base = (long)blockIdx.x * 128 * 64;

    #pragma unroll
    for (int it = 0; it < 4; ++it) {
        const int gidx = tid + it * 256;          // 0..1023 = r*8 + o
        const int r = gidx >> 3, o = gidx & 7;    // row r (n dim), k-octet o
        float4 va = *(const float4*)&fts[base + r * 64 + o * 8];
        float4 vb = *(const float4*)&fts[base + r * 64 + o * 8 + 4];
        short8 pk;
        pk[0] = f2bf(va.x); pk[1] = f2bf(va.y); pk[2] = f2bf(va.z); pk[3] = f2bf(va.w);
        pk[4] = f2bf(vb.x); pk[5] = f2bf(vb.y); pk[6] = f2bf(vb.z); pk[7] = f2bf(vb.w);
        *(short8*)&sB[(o >> 2) * 4160 + (r >> 4) * 520 + ((o & 3) * 16 + (r & 15)) * 8] = pk;
    }
    __syncthreads();

    const int wave = tid >> 6, lane = tid & 63;
    const int col = lane & 15, quad = lane >> 4;
    const f32x4 fz = {0.f, 0.f, 0.f, 0.f};
    f32x4 acc[2][4] = {{fz, fz, fz, fz}, {fz, fz, fz, fz}};
    const short8* WA = (const short8*)(wf + OFF_D0F);
    #pragma unroll
    for (int kt = 0; kt < 2; ++kt) {
        short8 af[4];
        #pragma unroll
        for (int mt = 0; mt < 4; ++mt) af[mt] = WA[(kt * 4 + mt) * 64 + lane];
        #pragma unroll
        for (int ni = 0; ni < 2; ++ni) {
            short8 bf_ = *(const short8*)&sB[kt * 4160 + (wave * 2 + ni) * 520 + lane * 8];
            #pragma unroll
            for (int mt = 0; mt < 4; ++mt)
                acc[ni][mt] = MFMA(af[mt], bf_, acc[ni][mt]);
        }
    }
    // C/D: element (cout = mt*16 + quad*4 + r, row = (wave*2+ni)*16 + col)
    #pragma unroll
    for (int mt = 0; mt < 4; ++mt) {
        const int c0 = mt * 16 + quad * 4;
        float4 b4 = *(const float4*)&b[c0];
        float4 g4 = *(const float4*)&g[c0];
        float4 e4 = *(const float4*)&be[c0];
        #pragma unroll
        for (int ni = 0; ni < 2; ++ni) {
            long rowg = (long)blockIdx.x * 128 + (wave * 2 + ni) * 16 + col;
            short4v sv;
            sv[0] = f2bf(g4.x * (eluf(acc[ni][mt][0] + b4.x) * BN_INV) + e4.x);
            sv[1] = f2bf(g4.y * (eluf(acc[ni][mt][1] + b4.y) * BN_INV) + e4.y);
            sv[2] = f2bf(g4.z * (eluf(acc[ni][mt][2] + b4.z) * BN_INV) + e4.z);
            sv[3] = f2bf(g4.w * (eluf(acc[ni][mt][3] + b4.w) * BN_INV) + e4.w);
            *(short4v*)&fl[rowg * 64 + c0] = sv;
        }
    }
}

// ---------------------------------------------------------------------------
// Fused XConv: 16 points/block, 256 threads (4 waves), MFMA everywhere.
// ---------------------------------------------------------------------------
__global__ __launch_bounds__(256) void k_xconv(
    const float* __restrict__ rep_pts, const float* __restrict__ pts,
    const int* __restrict__ pts_idx, const short* __restrict__ fl,
    const short* __restrict__ wf,
    const float* __restrict__ d1W, const float* __restrict__ d1b,
    const float* __restrict__ d1g, const float* __restrict__ d1be,
    const float* __restrict__ d2b, const float* __restrict__ d2g,
    const float* __restrict__ d2be,
    const float* __restrict__ xcb, const float* __restrict__ xd1b,
    const float* __restrict__ xd2b,
    const float* __restrict__ dwW, const float* __restrict__ dwb,
    const float* __restrict__ pwb,
    const float* __restrict__ endg, const float* __restrict__ endbe,
    float* __restrict__ out)
{
    __shared__ __align__(16) short s_catF[MPB * CATP];  // [p][c96][k16], 48.5 KB
    __shared__ __align__(16) short s_big[8448];         // h1F [16][66][8] -> X1+X2
    __shared__ __align__(16) short s_X0b[4160];         // X0 A-frags [8kt][65][8] -> dwF
    __shared__ __align__(16) short s_plF[1024];         // pl A-frags, K=64 (48 valid)

    const int tid = threadIdx.x;
    const int wave = tid >> 6, lane = tid & 63;
    const int col = lane & 15, quad = lane >> 4;
    const int n = blockIdx.x >> 6;                  // 64 blocks per batch
    const int pb = (blockIdx.x & 63) * MPB;
    const long prow0 = (long)n * PP + pb;
    short* s_h1F = s_big;                           // [mt16][66 slots][8]
    short* s_X1 = s_big;                            // [kt8][65 slots][8] = 4160
    short* s_X2 = s_big + 4160;                     // [p16][264]
    short* s_dwF = s_X0b;                           // [nb6][64][8] = 3072
    const f32x4 fz = {0.f, 0.f, 0.f, 0.f};
    const short8 zz = {0, 0, 0, 0, 0, 0, 0, 0};

    // ---- S0: plF tail zero + idx + local coords (regs) ----
    for (int i = 768 + tid; i < 1024; i += 256) s_plF[i] = 0;
    const int p0 = tid >> 4, k0 = tid & 15;
    const int idxv = pts_idx[(prow0 + p0) * 16 + k0];
    float x0, x1, x2;
    {
        const float* pp = pts + ((long)n * NUMPT + idxv) * 3;
        const float* rp = rep_pts + (prow0 + p0) * 3;
        x0 = pp[0] - rp[0]; x1 = pp[1] - rp[1]; x2 = pp[2] - rp[2];
        const float v[3] = {x0, x1, x2};
        #pragma unroll
        for (int d = 0; d < 3; ++d) {
            int kk = d * 16 + k0;
            s_plF[((kk >> 5) * 64 + ((kk >> 3) & 3) * 16 + p0) * 8 + (kk & 7)] = f2bf(v[d]);
        }
    }

    // ---- E: issue gather loads early ----
    short8 gv[8];
    {
        const short8* gp = (const short8*)(fl + ((long)n * NUMPT + idxv) * 64);
        #pragma unroll
        for (int i = 0; i < 8; ++i) gv[i] = gp[i];
    }

    // ---- S1: d1 from registers -> h1F packed b128 writes ----
    #pragma unroll
    for (int oct = 0; oct < 4; ++oct) {
        short8 v8;
        #pragma unroll
        for (int u = 0; u < 8; ++u) {
            int c = oct * 8 + u;
            float z = d1b[c] + x0 * d1W[c] + x1 * d1W[32 + c] + x2 * d1W[64 + c];
            v8[u] = f2bf(d1g[c] * (eluf(z) * BN_INV) + d1be[c]);
        }
        *(short8*)&s_h1F[(p0 * 66 + oct * 16 + k0) * 8] = v8;
    }

    // ---- E2: gathered features -> catF c-major [p][c][k] ----
    {
        const int gbase = p0 * CATP + 32 * 16 + k0;   // c starts at 32
        #pragma unroll
        for (int i = 0; i < 8; ++i) {
            #pragma unroll
            for (int u = 0; u < 8; ++u)
                s_catF[gbase + (i * 8 + u) * 16] = gv[i][u];
        }
    }
    __syncthreads();

    // ---- D: h2 = dense2(h1) MFMA (M=256,K=32,N=32) -> catF c<32, b64 packed ----
    {
        const short8* B = (const short8*)(wf + OFF_D2F);
        short8 b0 = B[lane], b1 = B[64 + lane];
        short8 a[4];
        #pragma unroll
        for (int mt0 = 0; mt0 < 4; ++mt0)
            a[mt0] = *(const short8*)&s_h1F[((wave * 4 + mt0) * 66 + lane) * 8];
        #pragma unroll
        for (int nb = 0; nb < 2; ++nb) {
            int c2 = nb * 16 + col;
            float bb = d2b[c2], gg = d2g[c2], bee = d2be[c2];
            #pragma unroll
            for (int mt0 = 0; mt0 < 4; ++mt0) {
                int mt = wave * 4 + mt0;             // == point p
                f32x4 acc = MFMA(a[mt0], nb ? b1 : b0, fz);
                short4v sv;
                #pragma unroll
                for (int r = 0; r < 4; ++r)          // r -> neighbor k = quad*4+r
                    sv[r] = f2bf(gg * (eluf(acc[r] + bb) * BN_INV) + bee);
                *(short4v*)&s_catF[mt * CATP + c2 * 16 + quad * 4] = sv;
            }
        }
    }

    // ---- F: X0 = elu(pl-lift) (M=16,K=64(48),N=256) -> X0 A-frags ----
    {
        short8 a0 = *(const short8*)&s_plF[lane * 8];
        short8 a1 = *(const short8*)&s_plF[(64 + lane) * 8];
        const short8* B = (const short8*)(wf + OFF_XCF);
        #pragma unroll
        for (int t = 0; t < 4; ++t) {
            int nb = wave * 4 + t;
            f32x4 acc = MFMA(a0, B[nb * 64 + lane], fz);
            acc = MFMA(a1, B[(16 + nb) * 64 + lane], acc);
            int q = nb * 16 + col;
            float bq = xcb[q];
            #pragma unroll
            for (int r = 0; r < 4; ++r) {
                int p = quad * 4 + r;
                s_X0b[(q >> 5) * 520 + (((q >> 3) & 3) * 16 + p) * 8 + (q & 7)]
                    = f2bf(eluf(acc[r] + bq));
            }
        }
    }
    __syncthreads();

    // ---- G: X1 = elu(X0 @ xd1W + b) (M=16,K=256,N=256) ----
    {
        short8 a[8];
        #pragma unroll
        for (int kt = 0; kt < 8; ++kt)
            a[kt] = *(const short8*)&s_X0b[kt * 520 + lane * 8];
        const short8* B = (const short8*)(wf + OFF_X1F);
        #pragma unroll
        for (int t = 0; t < 4; ++t) {
            int nb = wave * 4 + t;
            f32x4 acc = fz;
            #pragma unroll
            for (int kt = 0; kt < 8; ++kt)
                acc = MFMA(a[kt], B[(kt * 16 + nb) * 64 + lane], acc);
            int q = nb * 16 + col;
            float bq = xd1b[q];
            #pragma unroll
            for (int r = 0; r < 4; ++r) {
                int p = quad * 4 + r;
                s_X1[(q >> 5) * 520 + (((q >> 3) & 3) * 16 + p) * 8 + (q & 7)]
                    = f2bf(eluf(acc[r] + bq));
            }
        }
    }
    __syncthreads();

    // ---- G2: X2 = X1 @ xd2W + b (no elu) -> per-point H A-layout ----
    {
        short8 a[8];
        #pragma unroll
        for (int kt = 0; kt < 8; ++kt)
            a[kt] = *(const short8*)&s_X1[kt * 520 + lane * 8];
        const short8* B = (const short8*)(wf + OFF_X2F);
        #pragma unroll
        for (int t = 0; t < 4; ++t) {
            int nb = wave * 4 + t;                   // == i (row of 16x16 X)
            f32x4 acc = fz;
            #pragma unroll
            for (int kt = 0; kt < 8; ++kt)
                acc = MFMA(a[kt], B[(kt * 16 + nb) * 64 + lane], acc);
            float bq = xd2b[nb * 16 + col];          // j = col
            #pragma unroll
            for (int r = 0; r < 4; ++r) {
                int p = quad * 4 + r;
                s_X2[p * 264 + ((col >> 3) * 16 + nb) * 8 + (col & 7)] = f2bf(acc[r] + bq);
            }
        }
    }
    __syncthreads();

    // ---- H: per-point fts_X = X2(16x16) @ cat(16x96), fused depthwise ----
    {
        float4 wd0[6], wd1[6]; float2 bdw[6];
        #pragma unroll
        for (int nb = 0; nb < 6; ++nb) {
            int c = nb * 16 + col;
            wd0[nb] = *(const float4*)&dwW[(c * 2 + 0) * 16 + quad * 4];
            wd1[nb] = *(const float4*)&dwW[(c * 2 + 1) * 16 + quad * 4];
            bdw[nb] = *(const float2*)&dwb[c * 2];
        }
        #pragma unroll
        for (int pi = 0; pi < 4; ++pi) {
            int p = wave * 4 + pi;
            short8 afr = zz;
            if (lane < 32) afr = *(const short8*)&s_X2[p * 264 + lane * 8];
            #pragma unroll
            for (int nb = 0; nb < 6; ++nb) {
                short8 bfr = zz;
                if (lane < 32)
                    bfr = *(const short8*)&s_catF[p * CATP + (nb * 16 + col) * 16 + quad * 8];
                f32x4 acc = MFMA(afr, bfr, fz);      // C row = i, col = c
                float q0 = acc[0] * wd0[nb].x + acc[1] * wd0[nb].y + acc[2] * wd0[nb].z + acc[3] * wd0[nb].w;
                float q1 = acc[0] * wd1[nb].x + acc[1] * wd1[nb].y + acc[2] * wd1[nb].z + acc[3] * wd1[nb].w;
                q0 += __shfl_xor(q0, 16); q0 += __shfl_xor(q0, 32);
                q1 += __shfl_xor(q1, 16); q1 += __shfl_xor(q1, 32);
                if (quad == 0) {
                    int c2 = col * 2;                // kk = nb*32 + c2 + dm
                    int ad = (nb * 64 + (c2 >> 3) * 16 + p) * 8 + (c2 & 7);
                    short2v sv2;
                    sv2[0] = f2bf(q0 + bdw[nb].x);
                    sv2[1] = f2bf(q1 + bdw[nb].y);
                    *(short2v*)&s_dwF[ad] = sv2;
                }
            }
        }
    }
    __syncthreads();

    // ---- PW: out = BN(elu(dw @ pwW + b)) (M=16,K=192,N=128) ----
    {
        short8 a[6];
        #pragma unroll
        for (int kt = 0; kt < 6; ++kt)
            a[kt] = *(const short8*)&s_dwF[(kt * 64 + lane) * 8];
        const short8* B = (const short8*)(wf + OFF_PWF);
        #pragma unroll
        for (int t = 0; t < 2; ++t) {
            int nb = wave * 2 + t;
            f32x4 acc = fz;
            #pragma unroll
            for (int kt = 0; kt < 6; ++kt)
                acc = MFMA(a[kt], B[(kt * 8 + nb) * 64 + lane], acc);
            int o = nb * 16 + col;
            float bo = pwb[o], go = endg[o], beo = endbe[o];
            #pragma unroll
            for (int r = 0; r < 4; ++r) {
                int p = quad * 4 + r;
                out[(prow0 + p) * 128 + o] = go * (eluf(acc[r] + bo) * BN_INV) + beo;
            }
        }
    }
}

extern "C" void kernel_launch(void* const* d_in, const int* in_sizes, int n_in,
                              void* d_out, int out_size, void* d_ws, size_t ws_size,
                              hipStream_t stream) {
    const float* rep_pts = (const float*)d_in[0];
    const float* pts     = (const float*)d_in[1];
    const float* fts     = (const float*)d_in[2];
    const int*   pts_idx = (const int*)d_in[3];
    const float* d0W = (const float*)d_in[4];
    const float* d0b = (const float*)d_in[5];
    const float* d0g = (const float*)d_in[6];
    const float* d0be = (const float*)d_in[7];
    const float* d1W = (const float*)d_in[8];
    const float* d1b = (const float*)d_in[9];
    const float* d1g = (const float*)d_in[10];
    const float* d1be = (const float*)d_in[11];
    const float* d2W = (const float*)d_in[12];
    const float* d2b = (const float*)d_in[13];
    const float* d2g = (const float*)d_in[14];
    const float* d2be = (const float*)d_in[15];
    const float* xcW = (const float*)d_in[16];
    const float* xcb = (const float*)d_in[17];
    const float* xd1W = (const float*)d_in[18];
    const float* xd1b = (const float*)d_in[19];
    const float* xd2W = (const float*)d_in[20];
    const float* xd2b = (const float*)d_in[21];
    const float* dwW = (const float*)d_in[22];
    const float* dwb = (const float*)d_in[23];
    const float* pwW = (const float*)d_in[24];
    const float* pwb = (const float*)d_in[25];
    const float* endg = (const float*)d_in[26];
    const float* endbe = (const float*)d_in[27];
    float* out = (float*)d_out;

    short* wsS = (short*)d_ws;
    short* fl = wsS;                    // fts_l bf16: 8.39 MB
    short* wf = wsS + FTSL_ELEMS;       // frag weights: 354 KB

    k_prep<<<(TOT_FRAG + 255) / 256, 256, 0, stream>>>(d0W, xcW, xd1W, xd2W, d2W, pwW, wf);
    k_dense0m<<<(NBATCH * NUMPT) / 128, 256, 0, stream>>>(fts, wf, d0b, d0g, d0be, fl);
    k_xconv<<<NBATCH * (PP / MPB), 256, 0, stream>>>(
        rep_pts, pts, pts_idx, fl, wf,
        d1W, d1b, d1g, d1be, d2b, d2g, d2be,
        xcb, xd1b, xd2b, dwW, dwb, pwb, endg, endbe, out);
}